// Round 16
// baseline (893.900 us; speedup 1.0000x reference)
//
#include <hip/hip_runtime.h>
#include <stdint.h>

#define N_NODES 100000
#define N_EDGES 1600000
#define NB_SCAN 391   // ceil(N_NODES/256)

// Round 16. r15: 645 us. New bottleneck: k_scatter_ew 150 us, WRITE_SIZE 302 MB
// (5 scattered stores/edge -> ~5 write-allocated lines/edge). Fix: scatter the
// MINIMUM (csr_eidx only, 4 B/edge); agg preload gathers ei/ea via eidx and
// computes each edge's MLP LANE-PARALLEL in registers (16 fma x 3 + sigmoid per
// lane per 64 edges) — no ew buffer, exact fp32 -> absmax stays 0.0625.
// Dual-edge u32 gather core unchanged. ws ~33 MB.

__device__ __forceinline__ float bf2f(unsigned short s) {
    return __uint_as_float(((unsigned)s) << 16);
}
__device__ __forceinline__ unsigned short f2bf(float f) {
    unsigned u = __float_as_uint(f);
    u += 0x7fffu + ((u >> 16) & 1u);
    return (unsigned short)(u >> 16);
}
template <bool BF16>
__device__ __forceinline__ float LD(const void* p, size_t i) {
    if (BF16) return bf2f(((const unsigned short*)p)[i]);
    return ((const float*)p)[i];
}

// ---------------- dtype detection (proven) ----------------
__global__ void k_detect(const unsigned* __restrict__ xw, int* __restrict__ flag) {
    __shared__ int tot;
    if (threadIdx.x == 0) tot = 0;
    __syncthreads();
    int hit = 0;
    for (int i = threadIdx.x; i < 1024; i += 256) {
        unsigned e = (xw[i] >> 7) & 0xFFu;
        if (e >= 110u && e <= 135u) hit++;
    }
    atomicAdd(&tot, hit);
    __syncthreads();
    if (threadIdx.x == 0) *flag = (tot >= 512) ? 1 : 0;
}

// ---------------- CSR build ----------------

__global__ void k_hist(const int* __restrict__ ei, int* __restrict__ deg) {
    int e = blockIdx.x * 256 + threadIdx.x;
    if (e < N_EDGES) atomicAdd(&deg[ei[N_EDGES + e]], 1);
}

__global__ void k_scan_partial(const int* __restrict__ deg, int* __restrict__ bsum) {
    int t = threadIdx.x;
    int i = blockIdx.x * 256 + t;
    int v = (i < N_NODES) ? deg[i] : 0;
    for (int off = 32; off > 0; off >>= 1) v += __shfl_down(v, off, 64);
    __shared__ int ws4[4];
    if ((t & 63) == 0) ws4[t >> 6] = v;
    __syncthreads();
    if (t == 0) bsum[blockIdx.x] = ws4[0] + ws4[1] + ws4[2] + ws4[3];
}

__global__ void k_scan_mid(const int* __restrict__ bsum, int* __restrict__ boff) {
    __shared__ int s[512];
    int t = threadIdx.x;
    int v = (t < NB_SCAN) ? bsum[t] : 0;
    s[t] = v;
    __syncthreads();
    for (int off = 1; off < 512; off <<= 1) {
        int x = (t >= off) ? s[t - off] : 0;
        __syncthreads();
        s[t] += x;
        __syncthreads();
    }
    if (t < NB_SCAN) boff[t] = s[t] - v;   // exclusive
}

__global__ void k_scan_final(const int* __restrict__ deg, const int* __restrict__ boff,
                             int* __restrict__ row_start, int* __restrict__ cursor) {
    __shared__ int s[256];
    int t = threadIdx.x;
    int i = blockIdx.x * 256 + t;
    int v = (i < N_NODES) ? deg[i] : 0;
    s[t] = v;
    __syncthreads();
    for (int off = 1; off < 256; off <<= 1) {
        int x = (t >= off) ? s[t - off] : 0;
        __syncthreads();
        s[t] += x;
        __syncthreads();
    }
    if (i < N_NODES) {
        int rs = boff[blockIdx.x] + s[t] - v;
        row_start[i] = rs;
        cursor[i] = rs;
    }
}

// scatter: minimal — one 4B word (original edge index) per slot
__global__ void k_scatter(const int* __restrict__ ei, int* __restrict__ cursor,
                          int* __restrict__ csr_eidx) {
    int e = blockIdx.x * 256 + threadIdx.x;   // grid exact: 6250*256 = 1.6M
    int d = ei[N_EDGES + e];
    int slot = atomicAdd(&cursor[d], 1);
    csr_eidx[slot] = e;
}

// ---------------- layer 0 dense ----------------

template <bool BF>
__device__ __forceinline__ void dense0_body(const void* __restrict__ x,
                                            const void* __restrict__ W,
                                            const void* __restrict__ b,
                                            unsigned short* __restrict__ h,
                                            float* Wl, float (*xl)[32]) {
    int t = threadIdx.x, w = t >> 6, lane = t & 63;
    for (int i = t; i < 32 * 64; i += 256) Wl[i] = LD<BF>(W, i);
    int v0 = blockIdx.x * 16 + w * 4;
    if (lane < 32) {
        #pragma unroll
        for (int n = 0; n < 4; n++)
            xl[w * 4 + n][lane] = LD<BF>(x, (size_t)(v0 + n) * 32 + lane);
    }
    __syncthreads();
    float bias = LD<BF>(b, lane);
    float a0 = bias, a1 = bias, a2 = bias, a3 = bias;
    #pragma unroll 8
    for (int k = 0; k < 32; k++) {
        float wv = Wl[k * 64 + lane];
        a0 = fmaf(xl[w * 4 + 0][k], wv, a0);
        a1 = fmaf(xl[w * 4 + 1][k], wv, a1);
        a2 = fmaf(xl[w * 4 + 2][k], wv, a2);
        a3 = fmaf(xl[w * 4 + 3][k], wv, a3);
    }
    h[(size_t)(v0 + 0) * 64 + lane] = f2bf(a0);
    h[(size_t)(v0 + 1) * 64 + lane] = f2bf(a1);
    h[(size_t)(v0 + 2) * 64 + lane] = f2bf(a2);
    h[(size_t)(v0 + 3) * 64 + lane] = f2bf(a3);
}

__global__ void k_dense0(const int* __restrict__ flag, const void* x, const void* W,
                         const void* b, unsigned short* h) {
    __shared__ float Wl[32 * 64];
    __shared__ float xl[16][32];
    if (*flag) dense0_body<true>(x, W, b, h, Wl, xl);
    else       dense0_body<false>(x, W, b, h, Wl, xl);
}

// ---------------- aggregation: eidx preload + lane-parallel MLP + dual gathers
// Per 64-edge chunk: lane j loads eidx (coalesced), gathers src=ei[eidx] and
// ea[eidx], computes its edge's 16-unit MLP + sigmoid in registers (exact fp32).
// Then the dual-edge u32 gather loop: lanes 0-31 even edges / 32-63 odd edges,
// each lane holds channels (2c, 2c+1); __shfl_xor(32) merges parity halves.

template <bool BF>
__device__ __forceinline__ float2 agg_node2(int st, int d,
                                            const int* __restrict__ csr_eidx,
                                            const int* __restrict__ ei,
                                            const void* __restrict__ ea,
                                            const float* __restrict__ w1,   // LDS [32]
                                            const float* __restrict__ b1,   // LDS [16]
                                            const float* __restrict__ w2,   // LDS [16]
                                            float b2,
                                            const unsigned* __restrict__ hu,
                                            int lane) {
    int half = (lane >> 5) & 1;
    int c = lane & 31;
    float a0 = 0.f, a1 = 0.f;
    for (int base = 0; base < d; base += 64) {
        int cnt = min(64, d - base);
        int idx = 0;
        float ev = 0.f;
        if (lane < cnt) {
            int eidx = csr_eidx[st + base + lane];
            idx = ei[eidx];
            float e0 = LD<BF>(ea, (size_t)eidx * 2);
            float e1 = LD<BF>(ea, (size_t)eidx * 2 + 1);
            float z = b2;
            #pragma unroll
            for (int q = 0; q < 16; q++) {
                float hj = fmaf(e0, w1[q], fmaf(e1, w1[16 + q], b1[q]));
                z = fmaf(fmaxf(hj, 0.f), w2[q], z);
            }
            ev = 1.f / (1.f + expf(-z));
        }
        for (int j = 0; j < cnt; j += 8) {
            #pragma unroll
            for (int p = 0; p < 4; p++) {
                int jj = j + 2 * p + half;            // <= 63 always
                int s = __shfl(idx, jj, 64);          // lanes >= cnt: idx=0, ev=0
                float e = __shfl(ev, jj, 64);
                unsigned u = hu[(size_t)s * 32 + c];
                a0 = fmaf(e, bf2f((unsigned short)(u & 0xffffu)), a0);
                a1 = fmaf(e, bf2f((unsigned short)(u >> 16)), a1);
            }
        }
    }
    a0 += __shfl_xor(a0, 32, 64);
    a1 += __shfl_xor(a1, 32, 64);
    return make_float2(fmaxf(a0, 0.f), fmaxf(a1, 0.f));   // relu after every agg
}

// stage the layer's edge-MLP weights into LDS (first 65 threads)
template <bool BF>
__device__ __forceinline__ void stage_mlp(const void* ew1, int l,
                                          const void* eb1, const void* ew2, const void* eb2,
                                          float* sw1, float* sb1, float* sw2, float* sb2) {
    int t = threadIdx.x;
    if (t < 32) sw1[t] = LD<BF>(ew1, l * 32 + t);
    else if (t < 48) sb1[t - 32] = LD<BF>(eb1, l * 16 + t - 32);
    else if (t < 64) sw2[t - 48] = LD<BF>(ew2, l * 16 + t - 48);
    else if (t == 64) sb2[0] = LD<BF>(eb2, l);
}

// ---------------- fused: x = relu(agg(h_in)); h_out = x @ W + b ----------------
// 8 nodes/block (4 waves x 2 nodes); x fp32 in LDS only

template <bool BF>
__device__ __forceinline__ void fuse_body(const int* row_start, const int* deg,
                                          const int* csr_eidx, const int* ei, const void* ea,
                                          const void* ew1, int l, const void* eb1,
                                          const void* ew2, const void* eb2,
                                          const unsigned* hu,
                                          const void* W, const void* b,
                                          unsigned short* h_out,
                                          float* Wl, float (*xs)[64],
                                          float* sw1, float* sb1, float* sw2, float* sb2) {
    int t = threadIdx.x, w = t >> 6, lane = t & 63;
    stage_mlp<BF>(ew1, l, eb1, ew2, eb2, sw1, sb1, sw2, sb2);
    for (int i = t; i < 64 * 64; i += 256) Wl[i] = LD<BF>(W, l * 64 * 64 + i);
    __syncthreads();
    float b2v = sb2[0];
    int v0 = blockIdx.x * 8 + w * 2;
    #pragma unroll
    for (int n = 0; n < 2; n++) {
        int v = v0 + n;
        float2 r = agg_node2<BF>(row_start[v], deg[v], csr_eidx, ei, ea,
                                 sw1, sb1, sw2, b2v, hu, lane);
        if (lane < 32) {
            xs[w * 2 + n][lane * 2] = r.x;
            xs[w * 2 + n][lane * 2 + 1] = r.y;
        }
    }
    __syncthreads();
    float bias = LD<BF>(b, l * 64 + lane);
    float a0 = bias, a1 = bias;
    #pragma unroll 8
    for (int k = 0; k < 64; k++) {
        float wv = Wl[k * 64 + lane];
        a0 = fmaf(xs[w * 2 + 0][k], wv, a0);
        a1 = fmaf(xs[w * 2 + 1][k], wv, a1);
    }
    h_out[(size_t)(v0 + 0) * 64 + lane] = f2bf(a0);
    h_out[(size_t)(v0 + 1) * 64 + lane] = f2bf(a1);
}

__global__ void k_fuse(const int* __restrict__ flag,
                       const int* row_start, const int* deg, const int* csr_eidx,
                       const int* ei, const void* ea,
                       const void* ew1, int l, const void* eb1, const void* ew2, const void* eb2,
                       const unsigned* hu, const void* W, const void* b,
                       unsigned short* h_out) {
    __shared__ float Wl[64 * 64];
    __shared__ float xs[8][64];
    __shared__ float sw1[32], sb1[16], sw2[16], sb2[1];
    if (*flag) fuse_body<true>(row_start, deg, csr_eidx, ei, ea, ew1, l, eb1, ew2, eb2,
                               hu, W, b, h_out, Wl, xs, sw1, sb1, sw2, sb2);
    else       fuse_body<false>(row_start, deg, csr_eidx, ei, ea, ew1, l, eb1, ew2, eb2,
                                hu, W, b, h_out, Wl, xs, sw1, sb1, sw2, sb2);
}

// ---------------- fused final: x3 = relu(agg(h3)); heads -> out ---------------
// 16 nodes/block (4 waves x 4 nodes)

template <bool BF>
__device__ __forceinline__ void fuse_heads_body(
        const int* row_start, const int* deg, const int* csr_eidx,
        const int* ei, const void* ea,
        const void* ew1, const void* eb1, const void* ew2, const void* eb2,
        const unsigned* hu,
        const void* rh1w, const void* rh1b, const void* rh2w, const void* rh2b,
        const void* meanw, const void* meanb, const void* stdw, const void* stdb,
        const void* cls1w, const void* cls1b, const void* cls2w, const void* cls2b,
        void* __restrict__ out,
        float* s_rh1, float* s_cls1, float* s_rh2, float* s_cls2,
        float* s_rh1b, float* s_cls1b, float* s_rh2b, float* s_mw, float* s_sw,
        float* s_c2b, float* s_msb,
        float* sw1, float* sb1, float* sw2, float* sb2,
        float (*xs)[64], float (*r1)[32], float (*c1h)[32], float (*r2)[16]) {
    int t = threadIdx.x, w = t >> 6, lane = t & 63;
    stage_mlp<BF>(ew1, 3, eb1, ew2, eb2, sw1, sb1, sw2, sb2);
    for (int i = t; i < 2048; i += 256) { s_rh1[i] = LD<BF>(rh1w, i); s_cls1[i] = LD<BF>(cls1w, i); }
    for (int i = t; i < 512; i += 256) s_rh2[i] = LD<BF>(rh2w, i);
    if (t >= 128 && t < 192) s_cls2[t - 128] = LD<BF>(cls2w, t - 128);
    else if (t >= 192 && t < 224) { int i = t - 192; s_rh1b[i] = LD<BF>(rh1b, i); s_cls1b[i] = LD<BF>(cls1b, i); }
    else if (t >= 224 && t < 240) { int i = t - 224; s_rh2b[i] = LD<BF>(rh2b, i); s_mw[i] = LD<BF>(meanw, i); s_sw[i] = LD<BF>(stdw, i); }
    else if (t == 240) { s_msb[0] = LD<BF>(meanb, 0); s_msb[1] = LD<BF>(stdb, 0); }
    else if (t == 241) { s_c2b[0] = LD<BF>(cls2b, 0); s_c2b[1] = LD<BF>(cls2b, 1); }
    __syncthreads();
    float b2v = sb2[0];

    int v00 = blockIdx.x * 16;
    #pragma unroll
    for (int n = 0; n < 4; n++) {
        int idx = w * 4 + n;
        int v = v00 + idx;
        float2 r = agg_node2<BF>(row_start[v], deg[v], csr_eidx, ei, ea,
                                 sw1, sb1, sw2, b2v, hu, lane);
        if (lane < 32) {
            xs[idx][lane * 2] = r.x;
            xs[idx][lane * 2 + 1] = r.y;
        }
    }
    __syncthreads();

    #pragma unroll
    for (int n = 0; n < 4; n++) {
        int idx = w * 4 + n;
        int c = lane & 31;
        const float* Wp = (lane < 32) ? s_rh1 : s_cls1;
        float acc = (lane < 32) ? s_rh1b[c] : s_cls1b[c];
        #pragma unroll 8
        for (int k = 0; k < 64; k++) acc = fmaf(xs[idx][k], Wp[k * 32 + c], acc);
        acc = fmaxf(acc, 0.f);
        if (lane < 32) r1[idx][c] = acc; else c1h[idx][c] = acc;
    }
    __syncthreads();

    #pragma unroll
    for (int n = 0; n < 4; n++) {
        int idx = w * 4 + n;
        if (lane < 16) {
            float acc = s_rh2b[lane];
            #pragma unroll
            for (int k = 0; k < 32; k++) acc = fmaf(r1[idx][k], s_rh2[k * 16 + lane], acc);
            r2[idx][lane] = fmaxf(acc, 0.f);
        }
    }
    __syncthreads();

    #pragma unroll
    for (int n = 0; n < 4; n++) {
        int idx = w * 4 + n;
        int v = v00 + idx;
        if (lane == 0) {
            float m = s_msb[0];
            #pragma unroll
            for (int k = 0; k < 16; k++) m = fmaf(r2[idx][k], s_mw[k], m);
            if (BF) ((unsigned short*)out)[v] = f2bf(m); else ((float*)out)[v] = m;
        } else if (lane == 1) {
            float sv = s_msb[1];
            #pragma unroll
            for (int k = 0; k < 16; k++) sv = fmaf(r2[idx][k], s_sw[k], sv);
            float sp = fmaxf(sv, 0.f) + log1pf(expf(-fabsf(sv)));   // stable softplus
            if (BF) ((unsigned short*)out)[N_NODES + v] = f2bf(sp); else ((float*)out)[N_NODES + v] = sp;
        } else if (lane < 4) {
            int jj = lane - 2;
            float acc = s_c2b[jj];
            #pragma unroll
            for (int k = 0; k < 32; k++) acc = fmaf(c1h[idx][k], s_cls2[k * 2 + jj], acc);
            size_t pos = (size_t)2 * N_NODES + (size_t)v * 2 + jj;
            if (BF) ((unsigned short*)out)[pos] = f2bf(acc); else ((float*)out)[pos] = acc;
        }
    }
}

__global__ void k_fuse_heads(const int* __restrict__ flag,
                             const int* row_start, const int* deg, const int* csr_eidx,
                             const int* ei, const void* ea,
                             const void* ew1, const void* eb1, const void* ew2, const void* eb2,
                             const unsigned* hu,
                             const void* rh1w, const void* rh1b, const void* rh2w, const void* rh2b,
                             const void* meanw, const void* meanb, const void* stdw, const void* stdb,
                             const void* cls1w, const void* cls1b, const void* cls2w, const void* cls2b,
                             void* out) {
    __shared__ float s_rh1[64 * 32], s_cls1[64 * 32], s_rh2[32 * 16], s_cls2[32 * 2];
    __shared__ float s_rh1b[32], s_cls1b[32], s_rh2b[16], s_mw[16], s_sw[16], s_c2b[2], s_msb[2];
    __shared__ float sw1[32], sb1[16], sw2[16], sb2[1];
    __shared__ float xs[16][64], r1[16][32], c1h[16][32], r2[16][16];
    if (*flag)
        fuse_heads_body<true>(row_start, deg, csr_eidx, ei, ea, ew1, eb1, ew2, eb2, hu,
                              rh1w, rh1b, rh2w, rh2b, meanw, meanb, stdw, stdb,
                              cls1w, cls1b, cls2w, cls2b, out,
                              s_rh1, s_cls1, s_rh2, s_cls2, s_rh1b, s_cls1b, s_rh2b,
                              s_mw, s_sw, s_c2b, s_msb, sw1, sb1, sw2, sb2, xs, r1, c1h, r2);
    else
        fuse_heads_body<false>(row_start, deg, csr_eidx, ei, ea, ew1, eb1, ew2, eb2, hu,
                               rh1w, rh1b, rh2w, rh2b, meanw, meanb, stdw, stdb,
                               cls1w, cls1b, cls2w, cls2b, out,
                               s_rh1, s_cls1, s_rh2, s_cls2, s_rh1b, s_cls1b, s_rh2b,
                               s_mw, s_sw, s_c2b, s_msb, sw1, sb1, sw2, sb2, xs, r1, c1h, r2);
}

// ---------------- launch ----------------

extern "C" void kernel_launch(void* const* d_in, const int* in_sizes, int n_in,
                              void* d_out, int out_size, void* d_ws, size_t ws_size,
                              hipStream_t stream) {
    const void* x_in  = d_in[0];
    const int* ei     = (const int*)d_in[1];
    const void* ea    = d_in[2];
    const void* W0    = d_in[3];
    const void* b0    = d_in[4];
    const void* Ws    = d_in[5];
    const void* bs    = d_in[6];
    const void* ew1   = d_in[7];
    const void* eb1   = d_in[8];
    const void* ew2   = d_in[9];
    const void* eb2   = d_in[10];
    const void* rh1w  = d_in[11];
    const void* rh1b  = d_in[12];
    const void* rh2w  = d_in[13];
    const void* rh2b  = d_in[14];
    const void* meanw = d_in[15];
    const void* meanb = d_in[16];
    const void* stdw  = d_in[17];
    const void* stdb  = d_in[18];
    const void* cls1w = d_in[19];
    const void* cls1b = d_in[20];
    const void* cls2w = d_in[21];
    const void* cls2b = d_in[22];

    char* wsp = (char*)d_ws;
    auto alloc = [&](size_t bytes) -> char* {
        char* p = wsp;
        wsp += (bytes + 255) & ~(size_t)255;
        return p;
    };
    // footprint ~33 MB
    int* flag       = (int*)alloc(4);
    int* deg        = (int*)alloc((size_t)N_NODES * 4);
    int* row_start  = (int*)alloc((size_t)N_NODES * 4);
    int* cursor     = (int*)alloc((size_t)N_NODES * 4);
    int* bsum       = (int*)alloc((size_t)NB_SCAN * 4);
    int* boff       = (int*)alloc((size_t)NB_SCAN * 4);
    int* csr_eidx   = (int*)alloc((size_t)N_EDGES * 4);
    unsigned short* hA = (unsigned short*)alloc((size_t)N_NODES * 64 * 2);
    unsigned short* hB = (unsigned short*)alloc((size_t)N_NODES * 64 * 2);

    k_detect<<<1, 256, 0, stream>>>((const unsigned*)x_in, flag);
    hipMemsetAsync(deg, 0, (size_t)N_NODES * 4, stream);
    k_hist<<<6250, 256, 0, stream>>>(ei, deg);
    k_scan_partial<<<NB_SCAN, 256, 0, stream>>>(deg, bsum);
    k_scan_mid<<<1, 512, 0, stream>>>(bsum, boff);
    k_scan_final<<<NB_SCAN, 256, 0, stream>>>(deg, boff, row_start, cursor);
    k_scatter<<<6250, 256, 0, stream>>>(ei, cursor, csr_eidx);

    // h0 = x_in @ W0 + b0
    k_dense0<<<6250, 256, 0, stream>>>(flag, x_in, W0, b0, hA);

    unsigned short* hin = hA;
    unsigned short* hout = hB;
    for (int l = 0; l < 3; l++) {
        k_fuse<<<12500, 256, 0, stream>>>(flag, row_start, deg, csr_eidx, ei, ea,
                                          ew1, l, eb1, ew2, eb2,
                                          (const unsigned*)hin, Ws, bs, hout);
        unsigned short* tmp = hin; hin = hout; hout = tmp;
    }
    k_fuse_heads<<<6250, 256, 0, stream>>>(flag, row_start, deg, csr_eidx, ei, ea,
                                           ew1, eb1, ew2, eb2, (const unsigned*)hin,
                                           rh1w, rh1b, rh2w, rh2b, meanw, meanb,
                                           stdw, stdb, cls1w, cls1b, cls2w, cls2b,
                                           d_out);
}